// Round 3
// baseline (470.642 us; speedup 1.0000x reference)
//
#include <hip/hip_runtime.h>
#include <hip/hip_bf16.h>
#include <stdint.h>

// GraphAttentionLayer: out = softmax(h A h^T, axis=1) @ h,  h = X W^T + b
// N=8192, IN_F=256, D=OUT_F=128. adjacency_matrix (d_in[0]) is UNUSED.
//
// v3 over v2:
//  - register prefetch of next K/V tile (loads overlap the whole compute
//    phase instead of stalling at the staging barrier)
//  - V stored globally PRE-PERMUTED (prep) so the PV B-fragment is a single
//    ds_read_b128 (kslot-order c(j) = jp*32 + quad*8 + b*4 + r)
//  - XCD swizzle: split = bid&7 -> each XCD's L2 caches one split's K-stream
//
// ws layout (bytes):            size
//   h_hi  [8192][128] bf16      2 MB   @ 0
//   h_lo  [8192][128] bf16      2 MB   @ 2 MB
//   q_hi  [8192][128] bf16      2 MB   @ 4 MB   (Q = h @ A)
//   q_lo  [8192][128] bf16      2 MB   @ 6 MB
//   htp   [128][8192] bf16      2 MB   @ 8 MB   (h^T, PV-permuted within 64-blocks)
//   opart [8][8192][128] f32   32 MB   @ 10 MB  (split-K partials)
//   mpart [8][8192] f32       256 KB   @ 42 MB
//   lpart [8][8192] f32       256 KB   @ 42 MB + 256 KB

#define NN 8192
#define INF_ 256
#define D 128
#define BQ 128          // Q rows per block (4 waves x 32)
#define BK 64
#define KSPLIT 8
#define KSEG (NN / KSPLIT)
#define NTILE (KSEG / BK)
#define L2E 1.44269504088896340736f

typedef __attribute__((ext_vector_type(8))) short bf16x8;
typedef __attribute__((ext_vector_type(4))) float f32x4;
typedef __attribute__((ext_vector_type(4))) unsigned int uint4v;

// PV kslot permutation of a node index within its 64-block:
// j = jt*16 + q*4 + r  ->  c = (jt>>1)*32 + q*8 + (jt&1)*4 + r
__device__ __forceinline__ int pv_perm(int g) {
    const int jt = (g >> 4) & 3, q = (g >> 2) & 3, r = g & 3;
    return (g & ~63) | ((jt >> 1) * 32 + q * 8 + (jt & 1) * 4 + r);
}

// ---------------------------------------------------------------- prep ----
// h = X@W^T + b (fp32), Q = h@A (fp32); emit bf16 hi/lo splits + permuted h^T.
__global__ __launch_bounds__(256) void prep_kernel(
    const float* __restrict__ X, const float* __restrict__ W,
    const float* __restrict__ bias, const float* __restrict__ A,
    __hip_bfloat16* __restrict__ h_hi, __hip_bfloat16* __restrict__ h_lo,
    __hip_bfloat16* __restrict__ q_hi, __hip_bfloat16* __restrict__ q_lo,
    __hip_bfloat16* __restrict__ htp)
{
    __shared__ float xs[32][INF_];   // 32 KB
    __shared__ float hs[32][D];      // 16 KB
    const int tid  = threadIdx.x;
    const int row0 = blockIdx.x * 32;

    {   // stage X tile (32x256 f32) coalesced
        const f32x4* Xv = (const f32x4*)(X + (size_t)row0 * INF_);
        f32x4* xsv = (f32x4*)&xs[0][0];
        #pragma unroll
        for (int i = 0; i < 8; ++i) xsv[tid + i*256] = Xv[tid + i*256];
    }
    __syncthreads();

    const int c  = tid & 127;   // output column
    const int rh = tid >> 7;    // row half (0/1) -> rows rh*16..rh*16+15

    // ---- h = X W^T + b ----
    float acc[16];
    #pragma unroll
    for (int r = 0; r < 16; ++r) acc[r] = 0.f;
    const f32x4* Wv = (const f32x4*)(W + (size_t)c * INF_);
    for (int k4 = 0; k4 < INF_/4; ++k4) {
        f32x4 w4 = Wv[k4];
        #pragma unroll
        for (int r = 0; r < 16; ++r) {
            f32x4 x4 = ((const f32x4*)&xs[rh*16 + r][0])[k4];  // LDS broadcast
            acc[r] += x4[0]*w4[0] + x4[1]*w4[1] + x4[2]*w4[2] + x4[3]*w4[3];
        }
    }
    const float bc = bias[c];
    #pragma unroll
    for (int r = 0; r < 16; ++r) {
        const int row = rh*16 + r;
        const float hv = acc[r] + bc;
        hs[row][c] = hv;
        const __hip_bfloat16 hi = __float2bfloat16(hv);
        const float lo = hv - __bfloat162float(hi);
        h_hi[(size_t)(row0+row)*D + c] = hi;
        h_lo[(size_t)(row0+row)*D + c] = __float2bfloat16(lo);
        htp [(size_t)c*NN + pv_perm(row0 + row)] = hi;
    }
    __syncthreads();

    // ---- Q = h @ A ----
    float acc2[16];
    #pragma unroll
    for (int r = 0; r < 16; ++r) acc2[r] = 0.f;
    for (int d4 = 0; d4 < D/4; ++d4) {
        f32x4 hv4[16];
        #pragma unroll
        for (int r = 0; r < 16; ++r) hv4[r] = ((const f32x4*)&hs[rh*16 + r][0])[d4];
        #pragma unroll
        for (int dd = 0; dd < 4; ++dd) {
            const float a = A[(size_t)(d4*4 + dd)*D + c];   // coalesced over c
            #pragma unroll
            for (int r = 0; r < 16; ++r) acc2[r] += hv4[r][dd] * a;
        }
    }
    #pragma unroll
    for (int r = 0; r < 16; ++r) {
        const int row = rh*16 + r;
        const float tv = acc2[r];
        const __hip_bfloat16 hi = __float2bfloat16(tv);
        const float lo = tv - __bfloat162float(hi);
        q_hi[(size_t)(row0+row)*D + c] = hi;
        q_lo[(size_t)(row0+row)*D + c] = __float2bfloat16(lo);
    }
}

// --------------------------------------------------------------- flash ----
// flat grid 512 blocks, 256 threads (4 waves). split = bid&7 (XCD-resident
// K-stream), qblk = bid>>3. Wave w owns Q rows q0 + w*32 + it*16 + l16.
//
// MFMA operand facts (verified rounds 1-2):
//   A-frag 16x16x32: lane(l16,quad) holds A[m=l16][k=quad*8+0..7]
//   B-frag:          lane(l16,quad) holds B[n=l16][k=quad*8+0..7]
//   C:               reg r holds      C[m=quad*4+r][n=l16]
//
// S^T = K.Q^T (A=K, B=Q): lane's S^T entries: i=l16, j=jt*16+quad*4+r.
// P exits directly in PV A-operand layout under kslot relabeling
//   kslot quad*8+s <-> j=(s<4 ? 2jp : 2jp+1)*16 + quad*4 + (s&3);
// V is staged PRE-PERMUTED so the matching B-frag is one b128 read.
__global__ __launch_bounds__(256, 2) void flash_kernel(
    const __hip_bfloat16* __restrict__ q_hi, const __hip_bfloat16* __restrict__ q_lo,
    const __hip_bfloat16* __restrict__ k_hi, const __hip_bfloat16* __restrict__ k_lo,
    const __hip_bfloat16* __restrict__ htp,
    float* __restrict__ opart, float* __restrict__ mpart, float* __restrict__ lpart)
{
    __shared__ __hip_bfloat16 khi[BK][136];   // 17408 B (row rotate 4 banks)
    __shared__ __hip_bfloat16 klo[BK][136];   // 17408 B
    __shared__ __hip_bfloat16 vt[D][72];      // 18432 B (permuted cols)

    const int tid  = threadIdx.x;
    const int wave = tid >> 6;
    const int lane = tid & 63;
    const int l16  = lane & 15;
    const int quad = lane >> 4;
    const int bid   = blockIdx.x;
    const int split = bid & 7;               // same-XCD blocks share a split
    const int q0    = (bid >> 3) * BQ;
    const int jbase = split * KSEG;

    // per-thread staging offsets (loop-invariant)
    int gko[4], gvo[4], lko[4], lvo[4];
    #pragma unroll
    for (int i = 0; i < 4; ++i) {
        const int chunk = tid + i*256;               // 0..1023
        gko[i] = (chunk >> 4) * D  + (chunk & 15) * 8;
        lko[i] = (chunk >> 4) * 136 + (chunk & 15) * 8;
        gvo[i] = (chunk >> 3) * NN + (chunk & 7) * 8;
        lvo[i] = (chunk >> 3) * 72 + (chunk & 7) * 8;
    }
    __hip_bfloat16* khi0 = &khi[0][0];
    __hip_bfloat16* klo0 = &klo[0][0];
    __hip_bfloat16* vt0  = &vt[0][0];

    // Q fragments (B-operand; n=l16 selects the Q row) for both i-tiles
    bf16x8 bqh[2][4], bql[2][4];
    #pragma unroll
    for (int it = 0; it < 2; ++it) {
        const size_t qrow = (size_t)q0 + wave*32 + it*16 + l16;
        const __hip_bfloat16* qhp = q_hi + qrow*D;
        const __hip_bfloat16* qlp = q_lo + qrow*D;
        #pragma unroll
        for (int t = 0; t < 4; ++t) {
            bqh[it][t] = *(const bf16x8*)(qhp + t*32 + quad*8);
            bql[it][t] = *(const bf16x8*)(qlp + t*32 + quad*8);
        }
    }

    f32x4 oacc[2][8];
    #pragma unroll
    for (int it = 0; it < 2; ++it)
        #pragma unroll
        for (int i = 0; i < 8; ++i) oacc[it][i] = (f32x4){0.f, 0.f, 0.f, 0.f};
    float mi[2] = {-1e30f, -1e30f}, li[2] = {0.f, 0.f};

    // prefetch tile 0 into registers
    uint4v pkh[4], pkl[4], pvv[4];
    {
        const __hip_bfloat16* kh = k_hi + (size_t)jbase * D;
        const __hip_bfloat16* kl = k_lo + (size_t)jbase * D;
        const __hip_bfloat16* vp = htp + jbase;
        #pragma unroll
        for (int i = 0; i < 4; ++i) {
            pkh[i] = *(const uint4v*)(kh + gko[i]);
            pkl[i] = *(const uint4v*)(kl + gko[i]);
            pvv[i] = *(const uint4v*)(vp + gvo[i]);
        }
    }

    for (int tile = 0; tile < NTILE; ++tile) {
        __syncthreads();   // all waves done reading previous tile's LDS
        #pragma unroll
        for (int i = 0; i < 4; ++i) {
            *(uint4v*)(khi0 + lko[i]) = pkh[i];
            *(uint4v*)(klo0 + lko[i]) = pkl[i];
            *(uint4v*)(vt0  + lvo[i]) = pvv[i];
        }
        __syncthreads();

        if (tile + 1 < NTILE) {   // prefetch next tile; drains during compute
            const size_t nb = (size_t)(jbase + (tile + 1) * BK);
            const __hip_bfloat16* kh = k_hi + nb * D;
            const __hip_bfloat16* kl = k_lo + nb * D;
            const __hip_bfloat16* vp = htp + nb;
            #pragma unroll
            for (int i = 0; i < 4; ++i) {
                pkh[i] = *(const uint4v*)(kh + gko[i]);
                pkl[i] = *(const uint4v*)(kl + gko[i]);
                pvv[i] = *(const uint4v*)(vp + gvo[i]);
            }
        }

        // ---- S^T strips: st[it][jt] rows j=jt*16+quad*4+r, col i=l16
        f32x4 st[2][4];
        #pragma unroll
        for (int jt = 0; jt < 4; ++jt) {
            #pragma unroll
            for (int t = 0; t < 4; ++t) {
                const bf16x8 ah = *(const bf16x8*)(&khi[jt*16 + l16][t*32 + quad*8]);
                const bf16x8 al = *(const bf16x8*)(&klo[jt*16 + l16][t*32 + quad*8]);
                #pragma unroll
                for (int it = 0; it < 2; ++it) {
                    f32x4 acc = (t == 0) ? (f32x4){0.f,0.f,0.f,0.f} : st[it][jt];
                    acc = __builtin_amdgcn_mfma_f32_16x16x32_bf16(ah, bql[it][t], acc, 0, 0, 0);
                    acc = __builtin_amdgcn_mfma_f32_16x16x32_bf16(al, bqh[it][t], acc, 0, 0, 0);
                    acc = __builtin_amdgcn_mfma_f32_16x16x32_bf16(ah, bqh[it][t], acc, 0, 0, 0);
                    st[it][jt] = acc;
                }
            }
        }

        // ---- online softmax (lane owns row i = it*16 + l16)
        bf16x8 pb[2][2];
        #pragma unroll
        for (int it = 0; it < 2; ++it) {
            float vmax = st[it][0][0];
            #pragma unroll
            for (int jt = 0; jt < 4; ++jt)
                #pragma unroll
                for (int r = 0; r < 4; ++r) vmax = fmaxf(vmax, st[it][jt][r]);
            vmax = fmaxf(vmax, __shfl_xor(vmax, 16, 64));
            vmax = fmaxf(vmax, __shfl_xor(vmax, 32, 64));
            const float mnew  = fmaxf(mi[it], vmax);
            const float alpha = exp2f((mi[it] - mnew) * L2E);
            mi[it] = mnew;
            float sum = 0.f;
            #pragma unroll
            for (int jt = 0; jt < 4; ++jt)
                #pragma unroll
                for (int r = 0; r < 4; ++r) {
                    const float pv = exp2f((st[it][jt][r] - mnew) * L2E);
                    st[it][jt][r] = pv;
                    sum += pv;
                }
            sum += __shfl_xor(sum, 16, 64);
            sum += __shfl_xor(sum, 32, 64);
            li[it] = li[it] * alpha + sum;

            // rescale O (C rows are quad*4+r; alpha lives at lane l16==row)
            #pragma unroll
            for (int r = 0; r < 4; ++r) {
                const float ar = __shfl(alpha, quad*4 + r, 64);
                #pragma unroll
                for (int dt = 0; dt < 8; ++dt) oacc[it][dt][r] *= ar;
            }
            // pack P as PV A-operand (kslot relabeling: jt-pair per frag)
            #pragma unroll
            for (int jp = 0; jp < 2; ++jp) {
                bf16x8 f;
                #pragma unroll
                for (int r = 0; r < 4; ++r) {
                    f[r]     = __bfloat16_as_short(__float2bfloat16(st[it][2*jp  ][r]));
                    f[r + 4] = __bfloat16_as_short(__float2bfloat16(st[it][2*jp+1][r]));
                }
                pb[it][jp] = f;
            }
        }

        // ---- PV: O[m=i][n=d]; B-frag = one b128 (V pre-permuted)
        #pragma unroll
        for (int dt = 0; dt < 8; ++dt) {
            const __hip_bfloat16* vrow = &vt[dt*16 + l16][0];
            #pragma unroll
            for (int jp = 0; jp < 2; ++jp) {
                const bf16x8 bv = *(const bf16x8*)(vrow + jp*32 + quad*8);
                #pragma unroll
                for (int it = 0; it < 2; ++it)
                    oacc[it][dt] = __builtin_amdgcn_mfma_f32_16x16x32_bf16(
                        pb[it][jp], bv, oacc[it][dt], 0, 0, 0);
            }
        }
    }

    // ---- epilogue: split-K partials
    float* op = opart + ((size_t)split * NN + q0 + wave*32) * D;
    #pragma unroll
    for (int it = 0; it < 2; ++it) {
        #pragma unroll
        for (int r = 0; r < 4; ++r) {
            const int m = it*16 + quad*4 + r;
            #pragma unroll
            for (int dt = 0; dt < 8; ++dt)
                op[(size_t)m*D + dt*16 + l16] = oacc[it][dt][r];
        }
        if (quad == 0) {
            mpart[(size_t)split*NN + q0 + wave*32 + it*16 + l16] = mi[it];
            lpart[(size_t)split*NN + q0 + wave*32 + it*16 + l16] = li[it];
        }
    }
}

// ------------------------------------------------------------- combine ----
__global__ __launch_bounds__(256) void combine_kernel(
    const float* __restrict__ opart, const float* __restrict__ mpart,
    const float* __restrict__ lpart, float* __restrict__ out)
{
    const int idx = blockIdx.x * 256 + threadIdx.x;   // over 8192*128
    const int q = idx >> 7;
    float m = -1e30f;
    #pragma unroll
    for (int s = 0; s < KSPLIT; ++s) m = fmaxf(m, mpart[(size_t)s*NN + q]);
    float z = 0.f, o = 0.f;
    #pragma unroll
    for (int s = 0; s < KSPLIT; ++s) {
        const float w = exp2f((mpart[(size_t)s*NN + q] - m) * L2E);
        z += lpart[(size_t)s*NN + q] * w;
        o += opart[(size_t)s*NN*D + idx] * w;
    }
    out[idx] = o / z;
}

// ---------------------------------------------------------------- launch --
extern "C" void kernel_launch(void* const* d_in, const int* in_sizes, int n_in,
                              void* d_out, int out_size, void* d_ws, size_t ws_size,
                              hipStream_t stream)
{
    // setup_inputs order: adjacency(0, UNUSED), node_features(1), W(2), b(3), attn_weights(4)
    const float* X = (const float*)d_in[1];
    const float* W = (const float*)d_in[2];
    const float* b = (const float*)d_in[3];
    const float* A = (const float*)d_in[4];
    float* out = (float*)d_out;

    char* ws = (char*)d_ws;
    __hip_bfloat16* h_hi = (__hip_bfloat16*)(ws);
    __hip_bfloat16* h_lo = (__hip_bfloat16*)(ws + (size_t)(2u  << 20));
    __hip_bfloat16* q_hi = (__hip_bfloat16*)(ws + (size_t)(4u  << 20));
    __hip_bfloat16* q_lo = (__hip_bfloat16*)(ws + (size_t)(6u  << 20));
    __hip_bfloat16* htp  = (__hip_bfloat16*)(ws + (size_t)(8u  << 20));
    float* opart = (float*)(ws + (size_t)(10u << 20));
    float* mpart = (float*)(ws + (size_t)(42u << 20));
    float* lpart = (float*)(ws + (size_t)(42u << 20) + (256u << 10));

    prep_kernel<<<NN/32, 256, 0, stream>>>(X, W, b, A, h_hi, h_lo, q_hi, q_lo, htp);
    flash_kernel<<<(NN/BQ) * KSPLIT, 256, 0, stream>>>(
        q_hi, q_lo, h_hi, h_lo, htp, opart, mpart, lpart);
    combine_kernel<<<(NN*D)/256, 256, 0, stream>>>(opart, mpart, lpart, out);
}

// Round 4
// 429.318 us; speedup vs baseline: 1.0963x; 1.0963x over previous
//
#include <hip/hip_runtime.h>
#include <hip/hip_bf16.h>
#include <stdint.h>

// GraphAttentionLayer: out = softmax(h A h^T, axis=1) @ h,  h = X W^T + b
// N=8192, IN_F=256, D=OUT_F=128. adjacency_matrix (d_in[0]) is UNUSED.
//
// v4 over v3:
//  - REVERT register prefetch (VGPR pressure regression in r3)
//  - K/V staged via __builtin_amdgcn_global_load_lds width=16 (async DMA,
//    no VGPR round-trip, no staging VALU)
//  - since DMA forbids padding, bank conflicts broken by XOR chunk swizzle
//    baked into the GLOBAL layout by prep: K-arrays and htp are stored as
//    64-row-tile-major "LDS images" (16B chunk index ^= row&15 for K,
//    ^= d&7 for V) -> staging is a linear copy; frag reads stay b128,
//    2 lanes/bank (free).
//
// ws layout (bytes):            size
//   h_hi  [128 tiles][64][128] bf16 (swizzled K image)   2 MB @ 0
//   h_lo  same                                           2 MB @ 2 MB
//   q_hi  [8192][128] bf16 (plain)                       2 MB @ 4 MB
//   q_lo  [8192][128] bf16 (plain)                       2 MB @ 6 MB
//   htp   [128 tiles][128 d][64 j] bf16 (perm+swz V img) 2 MB @ 8 MB
//   opart [8][8192][128] f32                            32 MB @ 10 MB
//   mpart [8][8192] f32                               256 KB @ 42 MB
//   lpart [8][8192] f32                               256 KB @ 42 MB+256 KB

#define NN 8192
#define INF_ 256
#define D 128
#define BQ 128          // Q rows per block (4 waves x 32)
#define BK 64
#define KSPLIT 8
#define KSEG (NN / KSPLIT)
#define NTILE (KSEG / BK)
#define L2E 1.44269504088896340736f

typedef __attribute__((ext_vector_type(8))) short bf16x8;
typedef __attribute__((ext_vector_type(4))) float f32x4;

// async 16B global->LDS (gfx950: global_load_lds_dwordx4).
// LDS dest = wave-uniform base + lane*16; both pointers via integer casts.
__device__ __forceinline__ void gld16(const __hip_bfloat16* g, __hip_bfloat16* l) {
    __builtin_amdgcn_global_load_lds(
        (const __attribute__((address_space(1))) unsigned int*)(unsigned long long)(uintptr_t)g,
        (__attribute__((address_space(3))) unsigned int*)(unsigned long long)(uintptr_t)l,
        16, 0, 0);
}

// K-image element offset for global row `grow`, col c (tile-major):
// tile = grow>>6; within: row*128 + (chunk ^ (row&15))*8 + (c&7)
__device__ __forceinline__ size_t k_img(int grow, int c) {
    const int row = grow & 63;
    return (size_t)(grow >> 6) * 8192 + row * 128 + (((c >> 3) ^ (row & 15)) * 8) + (c & 7);
}

// V-image element offset for global node j, dim c:
// pv kslot perm within 64-block, then chunk swizzle by (c&7)
__device__ __forceinline__ size_t v_img(int j, int c) {
    const int jj = j & 63;
    const int jt = (jj >> 4) & 3, q = (jj >> 2) & 3, r = jj & 3;
    const int jp = (jt >> 1) * 32 + q * 8 + (jt & 1) * 4 + r;
    return (size_t)(j >> 6) * 8192 + c * 64 + (((jp >> 3) ^ (c & 7)) * 8) + (jp & 7);
}

// ---------------------------------------------------------------- prep ----
// h = X@W^T + b (fp32), Q = h@A (fp32); emit K images (hi/lo), V image, Q splits.
__global__ __launch_bounds__(256) void prep_kernel(
    const float* __restrict__ X, const float* __restrict__ W,
    const float* __restrict__ bias, const float* __restrict__ A,
    __hip_bfloat16* __restrict__ h_hi, __hip_bfloat16* __restrict__ h_lo,
    __hip_bfloat16* __restrict__ q_hi, __hip_bfloat16* __restrict__ q_lo,
    __hip_bfloat16* __restrict__ htp)
{
    __shared__ float xs[32][INF_];   // 32 KB
    __shared__ float hs[32][D];      // 16 KB
    const int tid  = threadIdx.x;
    const int row0 = blockIdx.x * 32;

    {   // stage X tile (32x256 f32) coalesced
        const f32x4* Xv = (const f32x4*)(X + (size_t)row0 * INF_);
        f32x4* xsv = (f32x4*)&xs[0][0];
        #pragma unroll
        for (int i = 0; i < 8; ++i) xsv[tid + i*256] = Xv[tid + i*256];
    }
    __syncthreads();

    const int c  = tid & 127;   // output column
    const int rh = tid >> 7;    // row half (0/1) -> rows rh*16..rh*16+15

    // ---- h = X W^T + b ----
    float acc[16];
    #pragma unroll
    for (int r = 0; r < 16; ++r) acc[r] = 0.f;
    const f32x4* Wv = (const f32x4*)(W + (size_t)c * INF_);
    for (int k4 = 0; k4 < INF_/4; ++k4) {
        f32x4 w4 = Wv[k4];
        #pragma unroll
        for (int r = 0; r < 16; ++r) {
            f32x4 x4 = ((const f32x4*)&xs[rh*16 + r][0])[k4];  // LDS broadcast
            acc[r] += x4[0]*w4[0] + x4[1]*w4[1] + x4[2]*w4[2] + x4[3]*w4[3];
        }
    }
    const float bc = bias[c];
    #pragma unroll
    for (int r = 0; r < 16; ++r) {
        const int row = rh*16 + r;
        const int grow = row0 + row;
        const float hv = acc[r] + bc;
        hs[row][c] = hv;
        const __hip_bfloat16 hi = __float2bfloat16(hv);
        const float lo = hv - __bfloat162float(hi);
        h_hi[k_img(grow, c)] = hi;
        h_lo[k_img(grow, c)] = __float2bfloat16(lo);
        htp [v_img(grow, c)] = hi;
    }
    __syncthreads();

    // ---- Q = h @ A ----
    float acc2[16];
    #pragma unroll
    for (int r = 0; r < 16; ++r) acc2[r] = 0.f;
    for (int d4 = 0; d4 < D/4; ++d4) {
        f32x4 hv4[16];
        #pragma unroll
        for (int r = 0; r < 16; ++r) hv4[r] = ((const f32x4*)&hs[rh*16 + r][0])[d4];
        #pragma unroll
        for (int dd = 0; dd < 4; ++dd) {
            const float a = A[(size_t)(d4*4 + dd)*D + c];   // coalesced over c
            #pragma unroll
            for (int r = 0; r < 16; ++r) acc2[r] += hv4[r][dd] * a;
        }
    }
    #pragma unroll
    for (int r = 0; r < 16; ++r) {
        const int row = rh*16 + r;
        const float tv = acc2[r];
        const __hip_bfloat16 hi = __float2bfloat16(tv);
        const float lo = tv - __bfloat162float(hi);
        q_hi[(size_t)(row0+row)*D + c] = hi;
        q_lo[(size_t)(row0+row)*D + c] = __float2bfloat16(lo);
    }
}

// --------------------------------------------------------------- flash ----
// flat grid 512 blocks, 256 threads (4 waves). split = bid&7 (XCD-resident
// K-stream), qblk = bid>>3. Wave w owns Q rows q0 + w*32 + it*16 + l16.
//
// MFMA operand facts (verified rounds 1-3):
//   A-frag 16x16x32: lane(l16,quad) holds A[m=l16][k=quad*8+0..7]
//   B-frag:          lane(l16,quad) holds B[n=l16][k=quad*8+0..7]
//   C:               reg r holds      C[m=quad*4+r][n=l16]
//
// S^T = K.Q^T (A=K, B=Q): lane's S^T entries: i=l16, j=jt*16+quad*4+r.
// P exits directly in PV A-operand layout under kslot relabeling
//   kslot quad*8+s <-> j=(s<4 ? 2jp : 2jp+1)*16 + quad*4 + (s&3);
// K/V staged by global_load_lds from pre-swizzled global images.
__global__ __launch_bounds__(256, 2) void flash_kernel(
    const __hip_bfloat16* __restrict__ q_hi, const __hip_bfloat16* __restrict__ q_lo,
    const __hip_bfloat16* __restrict__ k_hi, const __hip_bfloat16* __restrict__ k_lo,
    const __hip_bfloat16* __restrict__ htp,
    float* __restrict__ opart, float* __restrict__ mpart, float* __restrict__ lpart)
{
    __shared__ __hip_bfloat16 khi[BK*128];   // 16 KB  (swizzled image)
    __shared__ __hip_bfloat16 klo[BK*128];   // 16 KB
    __shared__ __hip_bfloat16 vt [D*64];     // 16 KB

    const int tid  = threadIdx.x;
    const int wave = tid >> 6;
    const int lane = tid & 63;
    const int l16  = lane & 15;
    const int quad = lane >> 4;
    const int bid   = blockIdx.x;
    const int split = bid & 7;               // same-XCD blocks share a split
    const int q0    = (bid >> 3) * BQ;
    const int tbase = split * NTILE;         // 64-row tile index base

    // Q fragments (B-operand; n=l16 selects the Q row) for both i-tiles
    bf16x8 bqh[2][4], bql[2][4];
    #pragma unroll
    for (int it = 0; it < 2; ++it) {
        const size_t qrow = (size_t)q0 + wave*32 + it*16 + l16;
        const __hip_bfloat16* qhp = q_hi + qrow*D;
        const __hip_bfloat16* qlp = q_lo + qrow*D;
        #pragma unroll
        for (int t = 0; t < 4; ++t) {
            bqh[it][t] = *(const bf16x8*)(qhp + t*32 + quad*8);
            bql[it][t] = *(const bf16x8*)(qlp + t*32 + quad*8);
        }
    }

    f32x4 oacc[2][8];
    #pragma unroll
    for (int it = 0; it < 2; ++it)
        #pragma unroll
        for (int i = 0; i < 8; ++i) oacc[it][i] = (f32x4){0.f, 0.f, 0.f, 0.f};
    float mi[2] = {-1e30f, -1e30f}, li[2] = {0.f, 0.f};

    for (int tile = 0; tile < NTILE; ++tile) {
        const size_t tb = (size_t)(tbase + tile) * 8192;
        __syncthreads();   // all waves done reading previous tile's LDS
        // async DMA: each wave copies its 4 chunks x 3 arrays (linear images)
        #pragma unroll
        for (int i = 0; i < 4; ++i) {
            const int cb = (i*4 + wave) * 64;              // wave-uniform chunk base
            const size_t ge = tb + (size_t)(cb + lane) * 8;  // global elem offset
            gld16(k_hi + ge, &khi[cb*8]);
            gld16(k_lo + ge, &klo[cb*8]);
            gld16(htp  + ge, &vt [cb*8]);
        }
        __syncthreads();   // drains vmcnt -> LDS image complete

        // ---- S^T strips: st[it][jt] rows j=jt*16+quad*4+r, col i=l16
        f32x4 st[2][4];
        #pragma unroll
        for (int jt = 0; jt < 4; ++jt) {
            #pragma unroll
            for (int t = 0; t < 4; ++t) {
                const int ko = (jt*16 + l16)*128 + (((t*4 + quad) ^ l16) * 8);
                const bf16x8 ah = *(const bf16x8*)(&khi[ko]);
                const bf16x8 al = *(const bf16x8*)(&klo[ko]);
                #pragma unroll
                for (int it = 0; it < 2; ++it) {
                    f32x4 acc = (t == 0) ? (f32x4){0.f,0.f,0.f,0.f} : st[it][jt];
                    acc = __builtin_amdgcn_mfma_f32_16x16x32_bf16(ah, bql[it][t], acc, 0, 0, 0);
                    acc = __builtin_amdgcn_mfma_f32_16x16x32_bf16(al, bqh[it][t], acc, 0, 0, 0);
                    acc = __builtin_amdgcn_mfma_f32_16x16x32_bf16(ah, bqh[it][t], acc, 0, 0, 0);
                    st[it][jt] = acc;
                }
            }
        }

        // ---- online softmax (lane owns row i = it*16 + l16)
        bf16x8 pb[2][2];
        #pragma unroll
        for (int it = 0; it < 2; ++it) {
            float vmax = st[it][0][0];
            #pragma unroll
            for (int jt = 0; jt < 4; ++jt)
                #pragma unroll
                for (int r = 0; r < 4; ++r) vmax = fmaxf(vmax, st[it][jt][r]);
            vmax = fmaxf(vmax, __shfl_xor(vmax, 16, 64));
            vmax = fmaxf(vmax, __shfl_xor(vmax, 32, 64));
            const float mnew  = fmaxf(mi[it], vmax);
            const float alpha = exp2f((mi[it] - mnew) * L2E);
            mi[it] = mnew;
            float sum = 0.f;
            #pragma unroll
            for (int jt = 0; jt < 4; ++jt)
                #pragma unroll
                for (int r = 0; r < 4; ++r) {
                    const float pv = exp2f((st[it][jt][r] - mnew) * L2E);
                    st[it][jt][r] = pv;
                    sum += pv;
                }
            sum += __shfl_xor(sum, 16, 64);
            sum += __shfl_xor(sum, 32, 64);
            li[it] = li[it] * alpha + sum;

            // rescale O (C rows are quad*4+r; alpha lives at lane l16==row)
            #pragma unroll
            for (int r = 0; r < 4; ++r) {
                const float ar = __shfl(alpha, quad*4 + r, 64);
                #pragma unroll
                for (int dt = 0; dt < 8; ++dt) oacc[it][dt][r] *= ar;
            }
            // pack P as PV A-operand (kslot relabeling: jt-pair per frag)
            #pragma unroll
            for (int jp = 0; jp < 2; ++jp) {
                bf16x8 f;
                #pragma unroll
                for (int r = 0; r < 4; ++r) {
                    f[r]     = __bfloat16_as_short(__float2bfloat16(st[it][2*jp  ][r]));
                    f[r + 4] = __bfloat16_as_short(__float2bfloat16(st[it][2*jp+1][r]));
                }
                pb[it][jp] = f;
            }
        }

        // ---- PV: O[m=i][n=d]; B-frag = one b128 from swizzled V image
        #pragma unroll
        for (int dt = 0; dt < 8; ++dt) {
            const int vo = (dt*16 + l16)*64;
            #pragma unroll
            for (int jp = 0; jp < 2; ++jp) {
                const bf16x8 bv = *(const bf16x8*)(&vt[vo + (((jp*4 + quad) ^ (l16 & 7)) * 8)]);
                #pragma unroll
                for (int it = 0; it < 2; ++it)
                    oacc[it][dt] = __builtin_amdgcn_mfma_f32_16x16x32_bf16(
                        pb[it][jp], bv, oacc[it][dt], 0, 0, 0);
            }
        }
    }

    // ---- epilogue: split-K partials
    float* op = opart + ((size_t)split * NN + q0 + wave*32) * D;
    #pragma unroll
    for (int it = 0; it < 2; ++it) {
        #pragma unroll
        for (int r = 0; r < 4; ++r) {
            const int m = it*16 + quad*4 + r;
            #pragma unroll
            for (int dt = 0; dt < 8; ++dt)
                op[(size_t)m*D + dt*16 + l16] = oacc[it][dt][r];
        }
        if (quad == 0) {
            mpart[(size_t)split*NN + q0 + wave*32 + it*16 + l16] = mi[it];
            lpart[(size_t)split*NN + q0 + wave*32 + it*16 + l16] = li[it];
        }
    }
}

// ------------------------------------------------------------- combine ----
__global__ __launch_bounds__(256) void combine_kernel(
    const float* __restrict__ opart, const float* __restrict__ mpart,
    const float* __restrict__ lpart, float* __restrict__ out)
{
    const int idx = blockIdx.x * 256 + threadIdx.x;   // over 8192*128
    const int q = idx >> 7;
    float m = -1e30f;
    #pragma unroll
    for (int s = 0; s < KSPLIT; ++s) m = fmaxf(m, mpart[(size_t)s*NN + q]);
    float z = 0.f, o = 0.f;
    #pragma unroll
    for (int s = 0; s < KSPLIT; ++s) {
        const float w = exp2f((mpart[(size_t)s*NN + q] - m) * L2E);
        z += lpart[(size_t)s*NN + q] * w;
        o += opart[(size_t)s*NN*D + idx] * w;
    }
    out[idx] = o / z;
}

// ---------------------------------------------------------------- launch --
extern "C" void kernel_launch(void* const* d_in, const int* in_sizes, int n_in,
                              void* d_out, int out_size, void* d_ws, size_t ws_size,
                              hipStream_t stream)
{
    // setup_inputs order: adjacency(0, UNUSED), node_features(1), W(2), b(3), attn_weights(4)
    const float* X = (const float*)d_in[1];
    const float* W = (const float*)d_in[2];
    const float* b = (const float*)d_in[3];
    const float* A = (const float*)d_in[4];
    float* out = (float*)d_out;

    char* ws = (char*)d_ws;
    __hip_bfloat16* h_hi = (__hip_bfloat16*)(ws);
    __hip_bfloat16* h_lo = (__hip_bfloat16*)(ws + (size_t)(2u  << 20));
    __hip_bfloat16* q_hi = (__hip_bfloat16*)(ws + (size_t)(4u  << 20));
    __hip_bfloat16* q_lo = (__hip_bfloat16*)(ws + (size_t)(6u  << 20));
    __hip_bfloat16* htp  = (__hip_bfloat16*)(ws + (size_t)(8u  << 20));
    float* opart = (float*)(ws + (size_t)(10u << 20));
    float* mpart = (float*)(ws + (size_t)(42u << 20));
    float* lpart = (float*)(ws + (size_t)(42u << 20) + (256u << 10));

    prep_kernel<<<NN/32, 256, 0, stream>>>(X, W, b, A, h_hi, h_lo, q_hi, q_lo, htp);
    flash_kernel<<<(NN/BQ) * KSPLIT, 256, 0, stream>>>(
        q_hi, q_lo, h_hi, h_lo, htp, opart, mpart, lpart);
    combine_kernel<<<(NN*D)/256, 256, 0, stream>>>(opart, mpart, lpart, out);
}

// Round 5
// 423.386 us; speedup vs baseline: 1.1116x; 1.0140x over previous
//
#include <hip/hip_runtime.h>
#include <hip/hip_bf16.h>
#include <stdint.h>

// GraphAttentionLayer: out = softmax(h A h^T, axis=1) @ h,  h = X W^T + b
// N=8192, IN_F=256, D=OUT_F=128. adjacency_matrix (d_in[0]) is UNUSED.
//
// v5 over v4:
//  - split-K partials stored NORMALIZED (O/l) in bf16: halves partial traffic
//    (32 MB -> 16 MB written, 16 MB read). combine reweights by g_s =
//    l_s * 2^(m_s - m). Quantization adds <=0.016 absmax (range +-5).
//  - combine vectorized: bf16x8 loads, two f32x4 stores per thread.
//
// ws layout (bytes):            size
//   h_hi  [128 tiles][64][128] bf16 (swizzled K image)   2 MB @ 0
//   h_lo  same                                           2 MB @ 2 MB
//   q_hi  [8192][128] bf16 (plain)                       2 MB @ 4 MB
//   q_lo  [8192][128] bf16 (plain)                       2 MB @ 6 MB
//   htp   [128 tiles][128 d][64 j] bf16 (perm+swz V img) 2 MB @ 8 MB
//   opart [8][8192][128] bf16 (normalized O/l)          16 MB @ 10 MB
//   mpart [8][8192] f32                               256 KB @ 26 MB
//   lpart [8][8192] f32                               256 KB @ 26 MB+256 KB

#define NN 8192
#define INF_ 256
#define D 128
#define BQ 128          // Q rows per block (4 waves x 32)
#define BK 64
#define KSPLIT 8
#define KSEG (NN / KSPLIT)
#define NTILE (KSEG / BK)
#define L2E 1.44269504088896340736f

typedef __attribute__((ext_vector_type(8))) short bf16x8;
typedef __attribute__((ext_vector_type(8))) unsigned short u16x8;
typedef __attribute__((ext_vector_type(4))) float f32x4;

// async 16B global->LDS (gfx950: global_load_lds_dwordx4).
// LDS dest = wave-uniform base + lane*16; both pointers via integer casts.
__device__ __forceinline__ void gld16(const __hip_bfloat16* g, __hip_bfloat16* l) {
    __builtin_amdgcn_global_load_lds(
        (const __attribute__((address_space(1))) unsigned int*)(unsigned long long)(uintptr_t)g,
        (__attribute__((address_space(3))) unsigned int*)(unsigned long long)(uintptr_t)l,
        16, 0, 0);
}

// K-image element offset for global row `grow`, col c (tile-major):
// tile = grow>>6; within: row*128 + (chunk ^ (row&15))*8 + (c&7)
__device__ __forceinline__ size_t k_img(int grow, int c) {
    const int row = grow & 63;
    return (size_t)(grow >> 6) * 8192 + row * 128 + (((c >> 3) ^ (row & 15)) * 8) + (c & 7);
}

// V-image element offset for global node j, dim c:
// pv kslot perm within 64-block, then chunk swizzle by (c&7)
__device__ __forceinline__ size_t v_img(int j, int c) {
    const int jj = j & 63;
    const int jt = (jj >> 4) & 3, q = (jj >> 2) & 3, r = jj & 3;
    const int jp = (jt >> 1) * 32 + q * 8 + (jt & 1) * 4 + r;
    return (size_t)(j >> 6) * 8192 + c * 64 + (((jp >> 3) ^ (c & 7)) * 8) + (jp & 7);
}

// ---------------------------------------------------------------- prep ----
// h = X@W^T + b (fp32), Q = h@A (fp32); emit K images (hi/lo), V image, Q splits.
__global__ __launch_bounds__(256) void prep_kernel(
    const float* __restrict__ X, const float* __restrict__ W,
    const float* __restrict__ bias, const float* __restrict__ A,
    __hip_bfloat16* __restrict__ h_hi, __hip_bfloat16* __restrict__ h_lo,
    __hip_bfloat16* __restrict__ q_hi, __hip_bfloat16* __restrict__ q_lo,
    __hip_bfloat16* __restrict__ htp)
{
    __shared__ float xs[32][INF_];   // 32 KB
    __shared__ float hs[32][D];      // 16 KB
    const int tid  = threadIdx.x;
    const int row0 = blockIdx.x * 32;

    {   // stage X tile (32x256 f32) coalesced
        const f32x4* Xv = (const f32x4*)(X + (size_t)row0 * INF_);
        f32x4* xsv = (f32x4*)&xs[0][0];
        #pragma unroll
        for (int i = 0; i < 8; ++i) xsv[tid + i*256] = Xv[tid + i*256];
    }
    __syncthreads();

    const int c  = tid & 127;   // output column
    const int rh = tid >> 7;    // row half (0/1) -> rows rh*16..rh*16+15

    // ---- h = X W^T + b ----
    float acc[16];
    #pragma unroll
    for (int r = 0; r < 16; ++r) acc[r] = 0.f;
    const f32x4* Wv = (const f32x4*)(W + (size_t)c * INF_);
    for (int k4 = 0; k4 < INF_/4; ++k4) {
        f32x4 w4 = Wv[k4];
        #pragma unroll
        for (int r = 0; r < 16; ++r) {
            f32x4 x4 = ((const f32x4*)&xs[rh*16 + r][0])[k4];  // LDS broadcast
            acc[r] += x4[0]*w4[0] + x4[1]*w4[1] + x4[2]*w4[2] + x4[3]*w4[3];
        }
    }
    const float bc = bias[c];
    #pragma unroll
    for (int r = 0; r < 16; ++r) {
        const int row = rh*16 + r;
        const int grow = row0 + row;
        const float hv = acc[r] + bc;
        hs[row][c] = hv;
        const __hip_bfloat16 hi = __float2bfloat16(hv);
        const float lo = hv - __bfloat162float(hi);
        h_hi[k_img(grow, c)] = hi;
        h_lo[k_img(grow, c)] = __float2bfloat16(lo);
        htp [v_img(grow, c)] = hi;
    }
    __syncthreads();

    // ---- Q = h @ A ----
    float acc2[16];
    #pragma unroll
    for (int r = 0; r < 16; ++r) acc2[r] = 0.f;
    for (int d4 = 0; d4 < D/4; ++d4) {
        f32x4 hv4[16];
        #pragma unroll
        for (int r = 0; r < 16; ++r) hv4[r] = ((const f32x4*)&hs[rh*16 + r][0])[d4];
        #pragma unroll
        for (int dd = 0; dd < 4; ++dd) {
            const float a = A[(size_t)(d4*4 + dd)*D + c];   // coalesced over c
            #pragma unroll
            for (int r = 0; r < 16; ++r) acc2[r] += hv4[r][dd] * a;
        }
    }
    #pragma unroll
    for (int r = 0; r < 16; ++r) {
        const int row = rh*16 + r;
        const float tv = acc2[r];
        const __hip_bfloat16 hi = __float2bfloat16(tv);
        const float lo = tv - __bfloat162float(hi);
        q_hi[(size_t)(row0+row)*D + c] = hi;
        q_lo[(size_t)(row0+row)*D + c] = __float2bfloat16(lo);
    }
}

// --------------------------------------------------------------- flash ----
// flat grid 512 blocks, 256 threads (4 waves). split = bid&7 (XCD-resident
// K-stream), qblk = bid>>3. Wave w owns Q rows q0 + w*32 + it*16 + l16.
//
// MFMA operand facts (verified rounds 1-4):
//   A-frag 16x16x32: lane(l16,quad) holds A[m=l16][k=quad*8+0..7]
//   B-frag:          lane(l16,quad) holds B[n=l16][k=quad*8+0..7]
//   C:               reg r holds      C[m=quad*4+r][n=l16]
//
// S^T = K.Q^T (A=K, B=Q): lane's S^T entries: i=l16, j=jt*16+quad*4+r.
// P exits directly in PV A-operand layout under kslot relabeling
//   kslot quad*8+s <-> j=(s<4 ? 2jp : 2jp+1)*16 + quad*4 + (s&3);
// K/V staged by global_load_lds from pre-swizzled global images.
__global__ __launch_bounds__(256, 2) void flash_kernel(
    const __hip_bfloat16* __restrict__ q_hi, const __hip_bfloat16* __restrict__ q_lo,
    const __hip_bfloat16* __restrict__ k_hi, const __hip_bfloat16* __restrict__ k_lo,
    const __hip_bfloat16* __restrict__ htp,
    __hip_bfloat16* __restrict__ opart, float* __restrict__ mpart,
    float* __restrict__ lpart)
{
    __shared__ __hip_bfloat16 khi[BK*128];   // 16 KB  (swizzled image)
    __shared__ __hip_bfloat16 klo[BK*128];   // 16 KB
    __shared__ __hip_bfloat16 vt [D*64];     // 16 KB

    const int tid  = threadIdx.x;
    const int wave = tid >> 6;
    const int lane = tid & 63;
    const int l16  = lane & 15;
    const int quad = lane >> 4;
    const int bid   = blockIdx.x;
    const int split = bid & 7;               // same-XCD blocks share a split
    const int q0    = (bid >> 3) * BQ;
    const int tbase = split * NTILE;         // 64-row tile index base

    // Q fragments (B-operand; n=l16 selects the Q row) for both i-tiles
    bf16x8 bqh[2][4], bql[2][4];
    #pragma unroll
    for (int it = 0; it < 2; ++it) {
        const size_t qrow = (size_t)q0 + wave*32 + it*16 + l16;
        const __hip_bfloat16* qhp = q_hi + qrow*D;
        const __hip_bfloat16* qlp = q_lo + qrow*D;
        #pragma unroll
        for (int t = 0; t < 4; ++t) {
            bqh[it][t] = *(const bf16x8*)(qhp + t*32 + quad*8);
            bql[it][t] = *(const bf16x8*)(qlp + t*32 + quad*8);
        }
    }

    f32x4 oacc[2][8];
    #pragma unroll
    for (int it = 0; it < 2; ++it)
        #pragma unroll
        for (int i = 0; i < 8; ++i) oacc[it][i] = (f32x4){0.f, 0.f, 0.f, 0.f};
    float mi[2] = {-1e30f, -1e30f}, li[2] = {0.f, 0.f};

    for (int tile = 0; tile < NTILE; ++tile) {
        const size_t tb = (size_t)(tbase + tile) * 8192;
        __syncthreads();   // all waves done reading previous tile's LDS
        // async DMA: each wave copies its 4 chunks x 3 arrays (linear images)
        #pragma unroll
        for (int i = 0; i < 4; ++i) {
            const int cb = (i*4 + wave) * 64;              // wave-uniform chunk base
            const size_t ge = tb + (size_t)(cb + lane) * 8;  // global elem offset
            gld16(k_hi + ge, &khi[cb*8]);
            gld16(k_lo + ge, &klo[cb*8]);
            gld16(htp  + ge, &vt [cb*8]);
        }
        __syncthreads();   // drains vmcnt -> LDS image complete

        // ---- S^T strips: st[it][jt] rows j=jt*16+quad*4+r, col i=l16
        f32x4 st[2][4];
        #pragma unroll
        for (int jt = 0; jt < 4; ++jt) {
            #pragma unroll
            for (int t = 0; t < 4; ++t) {
                const int ko = (jt*16 + l16)*128 + (((t*4 + quad) ^ l16) * 8);
                const bf16x8 ah = *(const bf16x8*)(&khi[ko]);
                const bf16x8 al = *(const bf16x8*)(&klo[ko]);
                #pragma unroll
                for (int it = 0; it < 2; ++it) {
                    f32x4 acc = (t == 0) ? (f32x4){0.f,0.f,0.f,0.f} : st[it][jt];
                    acc = __builtin_amdgcn_mfma_f32_16x16x32_bf16(ah, bql[it][t], acc, 0, 0, 0);
                    acc = __builtin_amdgcn_mfma_f32_16x16x32_bf16(al, bqh[it][t], acc, 0, 0, 0);
                    acc = __builtin_amdgcn_mfma_f32_16x16x32_bf16(ah, bqh[it][t], acc, 0, 0, 0);
                    st[it][jt] = acc;
                }
            }
        }

        // ---- online softmax (lane owns row i = it*16 + l16)
        bf16x8 pb[2][2];
        #pragma unroll
        for (int it = 0; it < 2; ++it) {
            float vmax = st[it][0][0];
            #pragma unroll
            for (int jt = 0; jt < 4; ++jt)
                #pragma unroll
                for (int r = 0; r < 4; ++r) vmax = fmaxf(vmax, st[it][jt][r]);
            vmax = fmaxf(vmax, __shfl_xor(vmax, 16, 64));
            vmax = fmaxf(vmax, __shfl_xor(vmax, 32, 64));
            const float mnew  = fmaxf(mi[it], vmax);
            const float alpha = exp2f((mi[it] - mnew) * L2E);
            mi[it] = mnew;
            float sum = 0.f;
            #pragma unroll
            for (int jt = 0; jt < 4; ++jt)
                #pragma unroll
                for (int r = 0; r < 4; ++r) {
                    const float pv = exp2f((st[it][jt][r] - mnew) * L2E);
                    st[it][jt][r] = pv;
                    sum += pv;
                }
            sum += __shfl_xor(sum, 16, 64);
            sum += __shfl_xor(sum, 32, 64);
            li[it] = li[it] * alpha + sum;

            // rescale O (C rows are quad*4+r; alpha lives at lane l16==row)
            #pragma unroll
            for (int r = 0; r < 4; ++r) {
                const float ar = __shfl(alpha, quad*4 + r, 64);
                #pragma unroll
                for (int dt = 0; dt < 8; ++dt) oacc[it][dt][r] *= ar;
            }
            // pack P as PV A-operand (kslot relabeling: jt-pair per frag)
            #pragma unroll
            for (int jp = 0; jp < 2; ++jp) {
                bf16x8 f;
                #pragma unroll
                for (int r = 0; r < 4; ++r) {
                    f[r]     = __bfloat16_as_short(__float2bfloat16(st[it][2*jp  ][r]));
                    f[r + 4] = __bfloat16_as_short(__float2bfloat16(st[it][2*jp+1][r]));
                }
                pb[it][jp] = f;
            }
        }

        // ---- PV: O[m=i][n=d]; B-frag = one b128 from swizzled V image
        #pragma unroll
        for (int dt = 0; dt < 8; ++dt) {
            const int vo = (dt*16 + l16)*64;
            #pragma unroll
            for (int jp = 0; jp < 2; ++jp) {
                const bf16x8 bv = *(const bf16x8*)(&vt[vo + (((jp*4 + quad) ^ (l16 & 7)) * 8)]);
                #pragma unroll
                for (int it = 0; it < 2; ++it)
                    oacc[it][dt] = __builtin_amdgcn_mfma_f32_16x16x32_bf16(
                        pb[it][jp], bv, oacc[it][dt], 0, 0, 0);
            }
        }
    }

    // ---- epilogue: NORMALIZED bf16 split-K partials (O/l), plus m & l
    __hip_bfloat16* op = opart + ((size_t)split * NN + q0 + wave*32) * D;
    #pragma unroll
    for (int it = 0; it < 2; ++it) {
        const float linv = 1.f / li[it];     // lane l16 holds row it*16+l16
        #pragma unroll
        for (int r = 0; r < 4; ++r) {
            const int m = it*16 + quad*4 + r;
            const float lr = __shfl(linv, quad*4 + r, 64);
            #pragma unroll
            for (int dt = 0; dt < 8; ++dt)
                op[(size_t)m*D + dt*16 + l16] = __float2bfloat16(oacc[it][dt][r] * lr);
        }
        if (quad == 0) {
            mpart[(size_t)split*NN + q0 + wave*32 + it*16 + l16] = mi[it];
            lpart[(size_t)split*NN + q0 + wave*32 + it*16 + l16] = li[it];
        }
    }
}

// ------------------------------------------------------------- combine ----
// out[q][d] = sum_s g_s * O'_s[q][d] / sum_s g_s,  g_s = l_s * 2^(m_s - m).
// One thread per 8 contiguous d of one q: bf16x8 loads, two f32x4 stores.
__global__ __launch_bounds__(256) void combine_kernel(
    const __hip_bfloat16* __restrict__ opart, const float* __restrict__ mpart,
    const float* __restrict__ lpart, float* __restrict__ out)
{
    const int idx = blockIdx.x * 256 + threadIdx.x;   // over 8192*16
    const int q  = idx >> 4;
    const int d8 = (idx & 15) * 8;
    float m = -1e30f;
    #pragma unroll
    for (int s = 0; s < KSPLIT; ++s) m = fmaxf(m, mpart[(size_t)s*NN + q]);
    float z = 0.f, o[8];
    #pragma unroll
    for (int e = 0; e < 8; ++e) o[e] = 0.f;
    #pragma unroll
    for (int s = 0; s < KSPLIT; ++s) {
        const float g = lpart[(size_t)s*NN + q] * exp2f((mpart[(size_t)s*NN + q] - m) * L2E);
        z += g;
        const u16x8 v = *(const u16x8*)(opart + ((size_t)s*NN + q)*D + d8);
        #pragma unroll
        for (int e = 0; e < 8; ++e)
            o[e] += g * __uint_as_float((unsigned)v[e] << 16);
    }
    const float zinv = 1.f / z;
    f32x4 lo, hi;
    #pragma unroll
    for (int e = 0; e < 4; ++e) { lo[e] = o[e] * zinv; hi[e] = o[e+4] * zinv; }
    *(f32x4*)(out + (size_t)q*D + d8)     = lo;
    *(f32x4*)(out + (size_t)q*D + d8 + 4) = hi;
}

// ---------------------------------------------------------------- launch --
extern "C" void kernel_launch(void* const* d_in, const int* in_sizes, int n_in,
                              void* d_out, int out_size, void* d_ws, size_t ws_size,
                              hipStream_t stream)
{
    // setup_inputs order: adjacency(0, UNUSED), node_features(1), W(2), b(3), attn_weights(4)
    const float* X = (const float*)d_in[1];
    const float* W = (const float*)d_in[2];
    const float* b = (const float*)d_in[3];
    const float* A = (const float*)d_in[4];
    float* out = (float*)d_out;

    char* ws = (char*)d_ws;
    __hip_bfloat16* h_hi = (__hip_bfloat16*)(ws);
    __hip_bfloat16* h_lo = (__hip_bfloat16*)(ws + (size_t)(2u  << 20));
    __hip_bfloat16* q_hi = (__hip_bfloat16*)(ws + (size_t)(4u  << 20));
    __hip_bfloat16* q_lo = (__hip_bfloat16*)(ws + (size_t)(6u  << 20));
    __hip_bfloat16* htp  = (__hip_bfloat16*)(ws + (size_t)(8u  << 20));
    __hip_bfloat16* opart = (__hip_bfloat16*)(ws + (size_t)(10u << 20));
    float* mpart = (float*)(ws + (size_t)(26u << 20));
    float* lpart = (float*)(ws + (size_t)(26u << 20) + (256u << 10));

    prep_kernel<<<NN/32, 256, 0, stream>>>(X, W, b, A, h_hi, h_lo, q_hi, q_lo, htp);
    flash_kernel<<<(NN/BQ) * KSPLIT, 256, 0, stream>>>(
        q_hi, q_lo, h_hi, h_lo, htp, opart, mpart, lpart);
    combine_kernel<<<(NN*16)/256, 256, 0, stream>>>(opart, mpart, lpart, out);
}